// Round 1
// baseline (40.524 us; speedup 1.0000x reference)
//
#include <hip/hip_runtime.h>
#include <math.h>

#define NY 74
#define NX 74
#define HH 512
#define WW 512
#define CC 3
#define BB 16

__global__ __launch_bounds__(256) void stb_kernel(
    const float* __restrict__ fmap, const float* __restrict__ theta,
    float* __restrict__ out, float* __restrict__ delta_out)
{
    const int total = BB * HH * WW;
    int idx = blockIdx.x * blockDim.x + threadIdx.x; // flat pixel index b*H*W + h*W + w
    if (idx >= total) return;
    int w = idx & (WW - 1);
    int h = (idx >> 9) & (HH - 1);
    int b = idx >> 18;

    // sx = sy = W / (nx-3) = 512/71; reference divides the f32 coordinate by
    // the (f32-rounded) scalar, so do exactly that.
    const float sx = (float)(512.0 / 71.0);

    float xw = (float)w;
    float yh = (float)h;
    float qx = xw / sx;
    float qy = yh / sx;
    float pxf = floorf(qx);
    float pyf = floorf(qy);
    float u = qx - pxf;
    float v = qy - pyf;
    int px = (int)pxf;
    int py = (int)pyf;

    float Bu[4], Bv[4];
    {
        float u2 = u * u, u3 = u2 * u;
        Bu[0] = (-u3 + 3.f * u2 - 3.f * u + 1.f) / 6.f;
        Bu[1] = (3.f * u3 - 6.f * u2 + 4.f) / 6.f;
        Bu[2] = (-3.f * u3 + 3.f * u2 + 3.f * u + 1.f) / 6.f;
        Bu[3] = u3 / 6.f;
        float v2 = v * v, v3 = v2 * v;
        Bv[0] = (-v3 + 3.f * v2 - 3.f * v + 1.f) / 6.f;
        Bv[1] = (3.f * v3 - 6.f * v2 + 4.f) / 6.f;
        Bv[2] = (-3.f * v3 + 3.f * v2 + 3.f * v + 1.f) / 6.f;
        Bv[3] = v3 / 6.f;
    }

    const float* thx = theta + (size_t)b * 2 * NY * NX; // theta[b,0,:,:]
    const float* thy = thx + NY * NX;                   // theta[b,1,:,:]

    // delta = sum_{a,c} Bu[a]*Bv[c]*theta[b, py+c, px+a]
    float dx = 0.f, dy = 0.f;
    #pragma unroll
    for (int c = 0; c < 4; ++c) {
        int row = (py + c) * NX + px;
        float ax = 0.f, ay = 0.f;
        #pragma unroll
        for (int a = 0; a < 4; ++a) {
            ax += Bu[a] * thx[row + a];
            ay += Bu[a] * thy[row + a];
        }
        dx += Bv[c] * ax;
        dy += Bv[c] * ay;
    }

    float xs = xw + dx;
    float ys = yh + dy;
    float x0f = floorf(xs);
    float y0f = floorf(ys);
    int x0 = (int)x0f;
    int y0 = (int)y0f;
    // reference: x1 = clip(x0_preclip + 1); then x0 = clip(x0)
    int x1 = min(max(x0 + 1, 0), WW - 1);
    int y1 = min(max(y0 + 1, 0), HH - 1);
    x0 = min(max(x0, 0), WW - 1);
    y0 = min(max(y0, 0), HH - 1);

    float x0c = (float)x0, x1c = (float)x1;
    float y0c = (float)y0, y1c = (float)y1;
    float wa = (x1c - xs) * (y1c - ys);
    float wb = (x1c - xs) * (ys - y0c);
    float wc = (xs - x0c) * (y1c - ys);
    float wd = (xs - x0c) * (ys - y0c);

    const float* fb = fmap + (size_t)b * HH * WW * CC;
    const float* Ia = fb + ((size_t)y0 * WW + x0) * CC;
    const float* Ibp = fb + ((size_t)y1 * WW + x0) * CC;
    const float* Ic = fb + ((size_t)y0 * WW + x1) * CC;
    const float* Id = fb + ((size_t)y1 * WW + x1) * CC;

    float* op = out + (size_t)idx * CC;
    #pragma unroll
    for (int ch = 0; ch < CC; ++ch) {
        op[ch] = wa * Ia[ch] + wb * Ibp[ch] + wc * Ic[ch] + wd * Id[ch];
    }

    delta_out[idx] = dx;           // delta[0][b][h][w]
    delta_out[total + idx] = dy;   // delta[1][b][h][w]
}

extern "C" void kernel_launch(void* const* d_in, const int* in_sizes, int n_in,
                              void* d_out, int out_size, void* d_ws, size_t ws_size,
                              hipStream_t stream) {
    const float* fmap  = (const float*)d_in[0];
    const float* theta = (const float*)d_in[1];
    float* out = (float*)d_out;
    float* delta = out + (size_t)BB * HH * WW * CC;

    const int total = BB * HH * WW;
    dim3 grid((total + 255) / 256), block(256);
    stb_kernel<<<grid, block, 0, stream>>>(fmap, theta, out, delta);
}